// Round 8
// baseline (253.611 us; speedup 1.0000x reference)
//
#include <hip/hip_runtime.h>

#define EPS   0.01f
#define ALPHA 0.1f
#define H     60

typedef _Float16 h2v __attribute__((ext_vector_type(2)));
typedef __fp16   fp16x2 __attribute__((ext_vector_type(2)));

__device__ __forceinline__ float softplusf(float x) {
    // stable: max(x,0) + log1p(exp(-|x|))
    float e = __expf(-fabsf(x));
    return fmaxf(x, 0.f) + __logf(1.f + e);
}

__device__ __forceinline__ h2v pk2h(float a, float b) {
    fp16x2 r = __builtin_amdgcn_cvt_pkrtz(a, b);   // v_cvt_pkrtz_f16_f32
    return __builtin_bit_cast(h2v, r);
}

// ws layout: [0]=g0 | ws+16: W2pk h2v[60*30]  (f16-packed W2 rows, pair over k)
#define WS_PK 16

// ---- setup: g0 scalar + f16-packed W2 rows ----
__global__ void setup_kernel(const float* __restrict__ W2, const float* __restrict__ b1,
                             const float* __restrict__ b2, const float* __restrict__ W3,
                             const float* __restrict__ b3, float* __restrict__ ws) {
    const int tid = threadIdx.x;
    h2v* W2pk = (h2v*)(ws + WS_PK);
    for (int idx = tid; idx < H * (H / 2); idx += 256) {
        const int j = idx / (H / 2), p = idx % (H / 2);
        W2pk[idx] = pk2h(W2[j * H + 2 * p], W2[j * H + 2 * p + 1]);
    }
    if (tid == 0) {
        float h1[H];
        for (int k = 0; k < H; ++k) h1[k] = softplusf(b1[k]);
        float z3 = b3[0];
        for (int j = 0; j < H; ++j) {
            float acc = b2[j];
            for (int k = 0; k < H; ++k) acc = fmaf(W2[j * H + k], h1[k], acc);
            z3 = fmaf(W3[j], softplusf(acc), z3);
        }
        ws[0] = softplusf(z3);
    }
}

// ---- main: one row per thread. Forward f32 (scalar W2 via s_load);
// backward G in packed f16 (v_pk_fma_f16). launch_bounds(256,2): VGPR budget 256
// so ~110 live floats stay in arch VGPRs (NO AGPR shuffling — round-7 lesson:
// (256,4) forced 64-VGPR cap -> h1v/Gpk went to AGPRs, +7K VALU cyc/wave). ----
__global__ __launch_bounds__(256, 2) void sdnn_kernel(
    const float* __restrict__ X,   const float* __restrict__ Wf,
    const float* __restrict__ W1,  const float* __restrict__ b1,
    const float* __restrict__ W2,  const float* __restrict__ b2,
    const float* __restrict__ W3,  const float* __restrict__ b3,
    const float* __restrict__ Wim2,const float* __restrict__ Wim3,
    const float* __restrict__ ws,  float* __restrict__ out, int B)
{
    const int row = blockIdx.x * 256 + threadIdx.x;
    if (row >= B) return;

    const h2v* __restrict__ W2pk = (const h2v*)(ws + WS_PK);

    const float2 xv = ((const float2*)X)[row];
    const float x0 = xv.x, x1 = xv.y;

    // layer 1: h1 = sp(W1 x + b1)
    float h1v[H];
#pragma unroll
    for (int k = 0; k < H; ++k)
        h1v[k] = softplusf(fmaf(W1[2 * k], x0, fmaf(W1[2 * k + 1], x1, b1[k])));

    // G packed f16 pairs over k
    h2v Gpk[H / 2];
#pragma unroll
    for (int p = 0; p < H / 2; ++p) { Gpk[p][0] = (_Float16)0.f; Gpk[p][1] = (_Float16)0.f; }

    const float wi30 = Wim3[0], wi31 = Wim3[1];
    float z3 = fmaf(wi30, x0, fmaf(wi31, x1, b3[0]));
    float gim0 = 0.f, gim1 = 0.f;

    for (int j = 0; j < H; ++j) {
        const float* __restrict__ wrow = &W2[j * H];
        float a0 = 0.f, a1 = 0.f, a2 = 0.f, a3 = 0.f;
#pragma unroll
        for (int k = 0; k < H; k += 4) {
            a0 = fmaf(wrow[k + 0], h1v[k + 0], a0);
            a1 = fmaf(wrow[k + 1], h1v[k + 1], a1);
            a2 = fmaf(wrow[k + 2], h1v[k + 2], a2);
            a3 = fmaf(wrow[k + 3], h1v[k + 3], a3);
        }
        const float z2 = ((a0 + a1) + (a2 + a3))
                       + fmaf(Wim2[2 * j], x0, fmaf(Wim2[2 * j + 1], x1, b2[j]));
        const float e2 = __expf(-fabsf(z2));
        const float h2 = fmaxf(z2, 0.f) + __logf(1.f + e2);
        const float w3j = W3[j];
        z3 = fmaf(w3j, h2, z3);
        const float tj = w3j * (1.f - __expf(-h2));   // W3[j]*sigmoid(z2_j)
        gim0 = fmaf(tj, Wim2[2 * j],     gim0);
        gim1 = fmaf(tj, Wim2[2 * j + 1], gim1);

        const h2v t2 = pk2h(tj, tj);
        const h2v* __restrict__ wpk = W2pk + j * (H / 2);
#pragma unroll
        for (int p = 0; p < H / 2; ++p) Gpk[p] += wpk[p] * t2;   // v_pk_fma_f16
    }

    // backward finish: u1_k = G_k * sigmoid(z1_k) (sigmoid from h1: 1-exp(-h1))
    float q0 = 0.f, q1 = 0.f;
#pragma unroll
    for (int p = 0; p < H / 2; ++p) {
        const float Ga = (float)Gpk[p][0];
        const float Gb = (float)Gpk[p][1];
        const float ua = Ga * (1.f - __expf(-h1v[2 * p]));
        const float ub = Gb * (1.f - __expf(-h1v[2 * p + 1]));
        q0 = fmaf(ua, W1[4 * p],     fmaf(ub, W1[4 * p + 2], q0));
        q1 = fmaf(ua, W1[4 * p + 1], fmaf(ub, W1[4 * p + 3], q1));
    }

    const float g0 = ws[0];
    const float g  = softplusf(z3);
    const float u3 = (g > g0) ? (1.f - __expf(-g)) : 0.f;

    const float dV0 = fmaf(2.f * EPS, x0, u3 * (wi30 + gim0 + q0));
    const float dV1 = fmaf(2.f * EPS, x1, u3 * (wi31 + gim1 + q1));

    const float V  = fmaxf(g - g0, 0.f) + EPS * fmaf(x0, x0, x1 * x1);
    const float f0 = fmaf(Wf[0], x0, Wf[1] * x1);
    const float f1 = fmaf(Wf[2], x0, Wf[3] * x1);
    const float stab = fmaf(ALPHA, V, fmaf(dV0, f0, dV1 * f1));
    const float s    = __fdividef(fmaxf(stab, 0.f), fmaf(dV0, dV0, dV1 * dV1));

    float2 o;
    o.x = f0 - dV0 * s;
    o.y = f1 - dV1 * s;
    ((float2*)out)[row] = o;
}

// ---- fallback (round-2 monolithic) if ws is too small ----
__global__ void g0_kernel(const float* __restrict__ W2, const float* __restrict__ b1,
                          const float* __restrict__ b2, const float* __restrict__ W3,
                          const float* __restrict__ b3, float* __restrict__ g0_out) {
    if (threadIdx.x != 0 || blockIdx.x != 0) return;
    float h1[H];
    for (int k = 0; k < H; ++k) h1[k] = softplusf(b1[k]);
    float z3 = b3[0];
    for (int j = 0; j < H; ++j) {
        float acc = b2[j];
        for (int k = 0; k < H; ++k) acc = fmaf(W2[j * H + k], h1[k], acc);
        z3 = fmaf(W3[j], softplusf(acc), z3);
    }
    g0_out[0] = softplusf(z3);
}

__global__ __launch_bounds__(256) void sdnn_mono_kernel(
    const float* __restrict__ X,   const float* __restrict__ Wf,
    const float* __restrict__ W1,  const float* __restrict__ b1,
    const float* __restrict__ W2,  const float* __restrict__ b2,
    const float* __restrict__ W3,  const float* __restrict__ b3,
    const float* __restrict__ Wim2,const float* __restrict__ Wim3,
    const float* __restrict__ g0p, float* __restrict__ out, int B)
{
    const int row = blockIdx.x * 256 + threadIdx.x;
    if (row >= B) return;
    const float2 xv = ((const float2*)X)[row];
    const float x0 = xv.x, x1 = xv.y;
    float h1v[H];
#pragma unroll
    for (int k = 0; k < H; ++k)
        h1v[k] = softplusf(fmaf(W1[2 * k], x0, fmaf(W1[2 * k + 1], x1, b1[k])));
    float G[H];
#pragma unroll
    for (int k = 0; k < H; ++k) G[k] = 0.f;
    const float wi30 = Wim3[0], wi31 = Wim3[1];
    float z3 = fmaf(wi30, x0, fmaf(wi31, x1, b3[0]));
    float gim0 = 0.f, gim1 = 0.f;
    for (int j = 0; j < H; ++j) {
        const float* __restrict__ wrow = &W2[j * H];
        float a0 = 0.f, a1 = 0.f, a2 = 0.f, a3 = 0.f;
#pragma unroll
        for (int k = 0; k < H; k += 4) {
            a0 = fmaf(wrow[k + 0], h1v[k + 0], a0);
            a1 = fmaf(wrow[k + 1], h1v[k + 1], a1);
            a2 = fmaf(wrow[k + 2], h1v[k + 2], a2);
            a3 = fmaf(wrow[k + 3], h1v[k + 3], a3);
        }
        float acc = ((a0 + a1) + (a2 + a3))
                  + fmaf(Wim2[2 * j], x0, fmaf(Wim2[2 * j + 1], x1, b2[j]));
        const float h2  = softplusf(acc);
        const float w3j = W3[j];
        z3 = fmaf(w3j, h2, z3);
        const float tj = w3j * (1.f - __expf(-h2));
        gim0 = fmaf(tj, Wim2[2 * j],     gim0);
        gim1 = fmaf(tj, Wim2[2 * j + 1], gim1);
#pragma unroll
        for (int k = 0; k < H; ++k) G[k] = fmaf(wrow[k], tj, G[k]);
    }
    const float g0 = g0p[0];
    const float g  = softplusf(z3);
    const float u3 = (g > g0) ? (1.f - __expf(-g)) : 0.f;
    float q0 = 0.f, q1 = 0.f;
#pragma unroll
    for (int k = 0; k < H; ++k) {
        const float u1 = G[k] * (1.f - __expf(-h1v[k]));
        q0 = fmaf(u1, W1[2 * k],     q0);
        q1 = fmaf(u1, W1[2 * k + 1], q1);
    }
    const float dV0 = fmaf(2.f * EPS, x0, u3 * (wi30 + gim0 + q0));
    const float dV1 = fmaf(2.f * EPS, x1, u3 * (wi31 + gim1 + q1));
    const float V  = fmaxf(g - g0, 0.f) + EPS * fmaf(x0, x0, x1 * x1);
    const float f0 = fmaf(Wf[0], x0, Wf[1] * x1);
    const float f1 = fmaf(Wf[2], x0, Wf[3] * x1);
    const float stab = fmaf(ALPHA, V, fmaf(dV0, f0, dV1 * f1));
    const float s    = __fdividef(fmaxf(stab, 0.f), fmaf(dV0, dV0, dV1 * dV1));
    float2 o;
    o.x = f0 - dV0 * s;
    o.y = f1 - dV1 * s;
    ((float2*)out)[row] = o;
}

extern "C" void kernel_launch(void* const* d_in, const int* in_sizes, int n_in,
                              void* d_out, int out_size, void* d_ws, size_t ws_size,
                              hipStream_t stream) {
    const float* X    = (const float*)d_in[0];
    const float* Wf   = (const float*)d_in[1];
    const float* W1   = (const float*)d_in[2];
    const float* b1   = (const float*)d_in[3];
    const float* W2   = (const float*)d_in[4];
    const float* b2   = (const float*)d_in[5];
    const float* W3   = (const float*)d_in[6];
    const float* b3   = (const float*)d_in[7];
    const float* Wim2 = (const float*)d_in[8];
    const float* Wim3 = (const float*)d_in[9];
    float* out = (float*)d_out;
    float* wsf = (float*)d_ws;

    const int B = in_sizes[0] / 2;
    const int nblk = (B + 255) / 256;

    const size_t need = (WS_PK + (size_t)H * (H / 2)) * 4;

    if (ws_size >= need) {
        hipLaunchKernelGGL(setup_kernel, dim3(1), dim3(256), 0, stream,
                           W2, b1, b2, W3, b3, wsf);
        hipLaunchKernelGGL(sdnn_kernel, dim3(nblk), dim3(256), 0, stream,
                           X, Wf, W1, b1, W2, b2, W3, b3, Wim2, Wim3, wsf, out, B);
    } else {
        hipLaunchKernelGGL(g0_kernel, dim3(1), dim3(64), 0, stream,
                           W2, b1, b2, W3, b3, wsf);
        hipLaunchKernelGGL(sdnn_mono_kernel, dim3(nblk), dim3(256), 0, stream,
                           X, Wf, W1, b1, W2, b2, W3, b3, Wim2, Wim3, wsf, out, B);
    }
}

// Round 10
// 241.297 us; speedup vs baseline: 1.0510x; 1.0510x over previous
//
#include <hip/hip_runtime.h>

#define EPS   0.01f
#define ALPHA 0.1f
#define H     60

typedef float f32x2 __attribute__((ext_vector_type(2)));

__device__ __forceinline__ float softplusf(float x) {
    // stable: max(x,0) + log1p(exp(-|x|))
    float e = __expf(-fabsf(x));
    return fmaxf(x, 0.f) + __logf(1.f + e);
}

// packed f32 FMA: acc(pair) += w(pair, SGPR) * h(pair, VGPR). "v"/"s" constraints
// pin operands to arch VGPRs/SGPRs — AGPRs can't satisfy them (round-7/8 lesson:
// allocator parks arrays in AGPRs and pays accvgpr copies; this forbids it).
__device__ __forceinline__ void pk_fma(f32x2& acc, f32x2 w, f32x2 h) {
    asm("v_pk_fma_f32 %0, %1, %2, %0" : "+v"(acc) : "s"(w), "v"(h));
}

// ---- setup: g0 scalar only ----
__global__ void g0_kernel(const float* __restrict__ W2, const float* __restrict__ b1,
                          const float* __restrict__ b2, const float* __restrict__ W3,
                          const float* __restrict__ b3, float* __restrict__ g0_out) {
    if (threadIdx.x != 0 || blockIdx.x != 0) return;
    float h1[H];
    for (int k = 0; k < H; ++k) h1[k] = softplusf(b1[k]);
    float z3 = b3[0];
    for (int j = 0; j < H; ++j) {
        float acc = b2[j];
        for (int k = 0; k < H; ++k) acc = fmaf(W2[j * H + k], h1[k], acc);
        z3 = fmaf(W3[j], softplusf(acc), z3);
    }
    g0_out[0] = softplusf(z3);
}

// ---- main: one row per thread; h1/G as float2 k-pairs; v_pk_fma_f32 throughout ----
__global__ __launch_bounds__(256)
__attribute__((amdgpu_waves_per_eu(2, 3)))
void sdnn_kernel(
    const float* __restrict__ X,   const float* __restrict__ Wf,
    const float* __restrict__ W1,  const float* __restrict__ b1,
    const float* __restrict__ W2,  const float* __restrict__ b2,
    const float* __restrict__ W3,  const float* __restrict__ b3,
    const float* __restrict__ Wim2,const float* __restrict__ Wim3,
    const float* __restrict__ g0p, float* __restrict__ out, int B)
{
    const int row = blockIdx.x * 256 + threadIdx.x;
    if (row >= B) return;

    const float2 xv = ((const float2*)X)[row];
    const float x0 = xv.x, x1 = xv.y;

    // layer 1: h1 pairs (f32)
    f32x2 h1p[H / 2];
#pragma unroll
    for (int p = 0; p < H / 2; ++p) {
        const float za = fmaf(W1[4 * p],     x0, fmaf(W1[4 * p + 1], x1, b1[2 * p]));
        const float zb = fmaf(W1[4 * p + 2], x0, fmaf(W1[4 * p + 3], x1, b1[2 * p + 1]));
        h1p[p].x = softplusf(za);
        h1p[p].y = softplusf(zb);
    }

    // G pairs (f32)
    f32x2 Gp[H / 2];
#pragma unroll
    for (int p = 0; p < H / 2; ++p) Gp[p] = (f32x2){0.f, 0.f};

    const float wi30 = Wim3[0], wi31 = Wim3[1];
    float z3 = fmaf(wi30, x0, fmaf(wi31, x1, b3[0]));
    float gim0 = 0.f, gim1 = 0.f;

    const f32x2* __restrict__ W2p = (const f32x2*)W2;   // row j = pairs [j*30 .. j*30+29]

    for (int j = 0; j < H; ++j) {
        const f32x2* __restrict__ wrow = &W2p[j * (H / 2)];
        // z2_j = W2[j,:]·h1 : 30 pk_fma, 4 partial pairs for ILP.
        // Pairs 0..27 in the 4-step loop (p<28!, round-9 bug was p<30 -> OOB
        // h1p[30..31] + double-counted 28,29), tail pairs 28,29 explicit.
        f32x2 a0 = {0.f, 0.f}, a1 = {0.f, 0.f}, a2 = {0.f, 0.f}, a3 = {0.f, 0.f};
#pragma unroll
        for (int p = 0; p < 28; p += 4) {
            pk_fma(a0, wrow[p + 0], h1p[p + 0]);
            pk_fma(a1, wrow[p + 1], h1p[p + 1]);
            pk_fma(a2, wrow[p + 2], h1p[p + 2]);
            pk_fma(a3, wrow[p + 3], h1p[p + 3]);
        }
        pk_fma(a0, wrow[28], h1p[28]);
        pk_fma(a1, wrow[29], h1p[29]);
        const float z2 = ((a0.x + a0.y) + (a1.x + a1.y)) + ((a2.x + a2.y) + (a3.x + a3.y))
                       + fmaf(Wim2[2 * j], x0, fmaf(Wim2[2 * j + 1], x1, b2[j]));
        const float e2 = __expf(-fabsf(z2));
        const float h2 = fmaxf(z2, 0.f) + __logf(1.f + e2);
        const float w3j = W3[j];
        z3 = fmaf(w3j, h2, z3);
        const float tj = w3j * (1.f - __expf(-h2));   // W3[j]*sigmoid(z2_j)
        gim0 = fmaf(tj, Wim2[2 * j],     gim0);
        gim1 = fmaf(tj, Wim2[2 * j + 1], gim1);

        f32x2 t2; t2.x = tj; t2.y = tj;
#pragma unroll
        for (int p = 0; p < H / 2; ++p) pk_fma(Gp[p], wrow[p], t2);   // G += W2[j,:] * tj
    }

    // backward finish: u1_k = G_k * sigmoid(z1_k); sigmoid = 1-exp(-h1)
    float q0 = 0.f, q1 = 0.f;
#pragma unroll
    for (int p = 0; p < H / 2; ++p) {
        const float ua = Gp[p].x * (1.f - __expf(-h1p[p].x));
        const float ub = Gp[p].y * (1.f - __expf(-h1p[p].y));
        q0 = fmaf(ua, W1[4 * p],     fmaf(ub, W1[4 * p + 2], q0));
        q1 = fmaf(ua, W1[4 * p + 1], fmaf(ub, W1[4 * p + 3], q1));
    }

    const float g0 = g0p[0];
    const float g  = softplusf(z3);
    const float u3 = (g > g0) ? (1.f - __expf(-g)) : 0.f;

    const float dV0 = fmaf(2.f * EPS, x0, u3 * (wi30 + gim0 + q0));
    const float dV1 = fmaf(2.f * EPS, x1, u3 * (wi31 + gim1 + q1));

    const float V  = fmaxf(g - g0, 0.f) + EPS * fmaf(x0, x0, x1 * x1);
    const float f0 = fmaf(Wf[0], x0, Wf[1] * x1);
    const float f1 = fmaf(Wf[2], x0, Wf[3] * x1);
    const float stab = fmaf(ALPHA, V, fmaf(dV0, f0, dV1 * f1));
    const float s    = __fdividef(fmaxf(stab, 0.f), fmaf(dV0, dV0, dV1 * dV1));

    float2 o;
    o.x = f0 - dV0 * s;
    o.y = f1 - dV1 * s;
    ((float2*)out)[row] = o;
}

extern "C" void kernel_launch(void* const* d_in, const int* in_sizes, int n_in,
                              void* d_out, int out_size, void* d_ws, size_t ws_size,
                              hipStream_t stream) {
    const float* X    = (const float*)d_in[0];
    const float* Wf   = (const float*)d_in[1];
    const float* W1   = (const float*)d_in[2];
    const float* b1   = (const float*)d_in[3];
    const float* W2   = (const float*)d_in[4];
    const float* b2   = (const float*)d_in[5];
    const float* W3   = (const float*)d_in[6];
    const float* b3   = (const float*)d_in[7];
    const float* Wim2 = (const float*)d_in[8];
    const float* Wim3 = (const float*)d_in[9];
    float* out = (float*)d_out;
    float* wsf = (float*)d_ws;

    const int B = in_sizes[0] / 2;
    const int nblk = (B + 255) / 256;

    hipLaunchKernelGGL(g0_kernel, dim3(1), dim3(64), 0, stream,
                       W2, b1, b2, W3, b3, wsf);
    hipLaunchKernelGGL(sdnn_kernel, dim3(nblk), dim3(256), 0, stream,
                       X, Wf, W1, b1, W2, b2, W3, b3, Wim2, Wim3, wsf, out, B);
}